// Round 5
// baseline (15335.562 us; speedup 1.0000x reference)
//
#include <hip/hip_runtime.h>

// ---------------- problem constants ----------------
#define NN      20000     // nodes per type
#define EE      320000    // edges per relation
#define ETOT    340000    // EE + NN self loops
#define FD      512       // raw feature dim
#define HH_     4         // heads
#define CD      128       // channels per head
#define HHD     512       // H*C
#define BG      64        // batch graphs
#define INNERD  64

// ---- bf16 <-> f32 via raw bits (internal buffers only) ----
__device__ __forceinline__ float bf2f(unsigned v) { return __uint_as_float(v << 16); }
__device__ __forceinline__ unsigned short f2bf(float f) {
    unsigned u = __float_as_uint(f);
    unsigned r = 0x7fffu + ((u >> 16) & 1u);
    return (unsigned short)((u + r) >> 16);
}
template <typename TA> __device__ __forceinline__ float ldA(const TA* p, size_t i);
template <> __device__ __forceinline__ float ldA<float>(const float* p, size_t i) { return p[i]; }
template <> __device__ __forceinline__ float ldA<unsigned short>(const unsigned short* p, size_t i) { return bf2f(p[i]); }

// ---------------- GEMM: C[M,128](bf16) = A[M,K] @ B[K, cols 0..127 of ldb](f32) ----
// 64x64 tile, 256 threads, 4x4 per thread, BK=16. grid (128/64, ceil(M/64))
template <typename TA>
__global__ __launch_bounds__(256) void gemm_kernel(
    const TA* __restrict__ A, const float* __restrict__ B, int ldb,
    unsigned short* __restrict__ C, int M, int K)
{
    __shared__ float sA[16][65];  // [k][m]
    __shared__ float sB[16][65];  // [k][n]
    const int tid = threadIdx.x;
    const int tileM = blockIdx.y * 64;
    const int tileN = blockIdx.x * 64;
    const int ty = tid >> 4, tx = tid & 15;
    float acc[4][4] = {};

    for (int k0 = 0; k0 < K; k0 += 16) {
        #pragma unroll
        for (int idx = tid; idx < 64 * 16; idx += 256) {
            int m = idx >> 4, k = idx & 15;
            int gm = tileM + m;
            sA[k][m] = (gm < M) ? ldA(A, (size_t)gm * K + k0 + k) : 0.f;
        }
        #pragma unroll
        for (int idx = tid; idx < 16 * 64; idx += 256) {
            int k = idx >> 6, n = idx & 63;
            sB[k][n] = B[(size_t)(k0 + k) * ldb + tileN + n];
        }
        __syncthreads();
        #pragma unroll
        for (int k = 0; k < 16; ++k) {
            float a[4], b[4];
            #pragma unroll
            for (int i = 0; i < 4; ++i) a[i] = sA[k][ty * 4 + i];
            #pragma unroll
            for (int j = 0; j < 4; ++j) b[j] = sB[k][tx * 4 + j];
            #pragma unroll
            for (int i = 0; i < 4; ++i)
                #pragma unroll
                for (int j = 0; j < 4; ++j)
                    acc[i][j] += a[i] * b[j];
        }
        __syncthreads();
    }
    #pragma unroll
    for (int i = 0; i < 4; ++i) {
        int gm = tileM + ty * 4 + i;
        if (gm >= M) continue;
        #pragma unroll
        for (int j = 0; j < 4; ++j)
            C[(size_t)gm * CD + tileN + tx * 4 + j] = f2bf(acc[i][j]);
    }
}

// ---------------- edge pass 1 (one head): p = exp(logit); s[dst] += p ----------------
// one 64-lane wave per edge; lane covers 2 of the 128 channels; xl/xr internal bf16
__global__ __launch_bounds__(256) void edge_logits_h(
    const int* __restrict__ ei,
    const unsigned short* __restrict__ xl, const unsigned short* __restrict__ xr,
    const float* __restrict__ att,             // 128 f32 for this (rel, head)
    unsigned short* __restrict__ p,            // [ETOT] bf16
    float* __restrict__ s)                     // [NN] f32, zeroed
{
    int wave = (int)(((size_t)blockIdx.x * blockDim.x + threadIdx.x) >> 6);
    int lane = threadIdx.x & 63;
    if (wave >= ETOT) return;
    int src, dst;
    if (wave < EE) { src = ei[wave]; dst = ei[EE + wave]; }
    else           { src = dst = wave - EE; }

    unsigned ua = *reinterpret_cast<const unsigned*>(xl + (size_t)src * CD + lane * 2);
    unsigned ub = *reinterpret_cast<const unsigned*>(xr + (size_t)dst * CD + lane * 2);
    float v0 = bf2f(ua & 0xffffu) + bf2f(ub & 0xffffu);
    float v1 = bf2f(ua >> 16)     + bf2f(ub >> 16);
    v0 = (v0 > 0.f) ? v0 : 0.2f * v0;   // leaky_relu 0.2
    v1 = (v1 > 0.f) ? v1 : 0.2f * v1;
    float partial = v0 * att[lane * 2] + v1 * att[lane * 2 + 1];
    #pragma unroll
    for (int off = 1; off < 64; off <<= 1)
        partial += __shfl_xor(partial, off);
    if (lane == 0) {
        float pe = expf(partial);       // logits O(1); alpha invariant to max-shift
        p[wave] = f2bf(pe);
        atomicAdd(&s[dst], pe);
    }
}

// ---------------- edge pass 2 (one head): acc[dst,c] += alpha * xl[src,c] ----------------
__global__ __launch_bounds__(256) void edge_aggr_h(
    const int* __restrict__ ei,
    const unsigned short* __restrict__ xl,
    const unsigned short* __restrict__ p, const float* __restrict__ s,
    float* __restrict__ acc)                   // [NN*CD] f32
{
    int wave = (int)(((size_t)blockIdx.x * blockDim.x + threadIdx.x) >> 6);
    int lane = threadIdx.x & 63;
    if (wave >= ETOT) return;
    int src, dst;
    if (wave < EE) { src = ei[wave]; dst = ei[EE + wave]; }
    else           { src = dst = wave - EE; }

    float alpha = bf2f(p[wave]) / fmaxf(s[dst], 1e-16f);
    unsigned ua = *reinterpret_cast<const unsigned*>(xl + (size_t)src * CD + lane * 2);
    float* ad = acc + (size_t)dst * CD + lane * 2;
    atomicAdd(ad,     alpha * bf2f(ua & 0xffffu));
    atomicAdd(ad + 1, alpha * bf2f(ua >> 16));
}

// ---------------- finalize (layer 0): z = tanh(acc + sum_h biases), bf16 out ----------------
__global__ __launch_bounds__(256) void finalize_kernel(
    const float* __restrict__ acc,
    const float* __restrict__ bA, const float* __restrict__ bB,
    unsigned short* __restrict__ z)
{
    int idx = blockIdx.x * blockDim.x + threadIdx.x;
    if (idx >= NN * CD) return;
    int c = idx & 127;
    float bias = 0.f;
    #pragma unroll
    for (int h = 0; h < HH_; ++h)
        bias += bA[h * CD + c] + bB[h * CD + c];
    z[idx] = f2bf(tanhf(acc[idx] + bias));
}

// ---------------- finalize (layer 1) fused with pooling ----------------
__global__ __launch_bounds__(256) void pool_fused_kernel(
    const float* __restrict__ acc,
    const float* __restrict__ bA, const float* __restrict__ bB,
    const int* __restrict__ batch, float* __restrict__ pool)
{
    int idx = blockIdx.x * blockDim.x + threadIdx.x;
    if (idx >= NN * CD) return;
    int node = idx >> 7, c = idx & 127;
    float bias = 0.f;
    #pragma unroll
    for (int h = 0; h < HH_; ++h)
        bias += bA[h * CD + c] + bB[h * CD + c];
    float v = tanhf(acc[idx] + bias);
    atomicAdd(&pool[(size_t)batch[node] * CD + c], v);
}

// ---------------- head: tanh(pool), small GEMVs, sigmoid; f32 out ----------------
__global__ __launch_bounds__(128) void head_kernel(
    const float* __restrict__ pool_i, const float* __restrict__ pool_j,
    const float* __restrict__ W_out, const float* __restrict__ b_out,
    const float* __restrict__ W_i, const float* __restrict__ b_i,
    const float* __restrict__ W_j, const float* __restrict__ b_j,
    float* __restrict__ out)
{
    int b = blockIdx.x;     // 64 graphs
    int t = threadIdx.x;    // 128 threads
    __shared__ float pi[CD], pj[CD];
    pi[t] = tanhf(pool_i[(size_t)b * CD + t]);
    pj[t] = tanhf(pool_j[(size_t)b * CD + t]);
    __syncthreads();
    if (t < INNERD) {
        float a = b_i[t];
        for (int c = 0; c < CD; ++c) a += pi[c] * W_i[c * INNERD + t];
        out[BG + (size_t)b * INNERD + t] = a;
    } else {
        int k = t - INNERD;
        float a = b_j[k];
        for (int c = 0; c < CD; ++c) a += pj[c] * W_j[c * INNERD + k];
        out[BG + BG * INNERD + (size_t)b * INNERD + k] = a;
    }
    if (t == 0) {
        float a = b_out[0];
        for (int c = 0; c < CD; ++c) a += (pi[c] + pj[c]) * W_out[c];
        out[b] = 1.f / (1.f + expf(-a));
    }
}

// ---------------- host-side: one relation-group (two relations -> one acc) ----------------
template <typename TA>
static void run_group(const TA* srcs[2], const TA* dsts[2],
                      const int* eis[2], const int rids[2], int K,
                      const float* Wl, const float* Wr, const float* att,
                      unsigned short* xl, unsigned short* xr,
                      unsigned short* pbuf, float* sbuf, float* acc,
                      hipStream_t stream)
{
    hipMemsetAsync(acc, 0, (size_t)NN * CD * sizeof(float), stream);
    dim3 gg(CD / 64, (NN + 63) / 64);
    const int eblocks = ETOT / 4;   // 4 waves per 256-thread block

    for (int q = 0; q < 2; ++q) {
        int r = rids[q];
        for (int h = 0; h < HH_; ++h) {
            const float* WlS = Wl + (size_t)r * K * HHD + h * CD;
            const float* WrS = Wr + (size_t)r * K * HHD + h * CD;
            gemm_kernel<TA><<<gg, 256, 0, stream>>>(srcs[q], WlS, HHD, xl, NN, K);
            gemm_kernel<TA><<<gg, 256, 0, stream>>>(dsts[q], WrS, HHD, xr, NN, K);
            hipMemsetAsync(sbuf, 0, (size_t)NN * sizeof(float), stream);
            edge_logits_h<<<eblocks, 256, 0, stream>>>(
                eis[q], xl, xr, att + (size_t)r * HHD + h * CD, pbuf, sbuf);
            edge_aggr_h<<<eblocks, 256, 0, stream>>>(
                eis[q], xl, pbuf, sbuf, acc);
        }
    }
}

extern "C" void kernel_launch(void* const* d_in, const int* in_sizes, int n_in,
                              void* d_out, int out_size, void* d_ws, size_t ws_size,
                              hipStream_t stream)
{
    const float* x_i   = (const float*)d_in[0];
    const float* x_j   = (const float*)d_in[1];
    const int* ei_ii   = (const int*)d_in[2];
    const int* ei_jj   = (const int*)d_in[3];
    const int* ei_ij   = (const int*)d_in[4];
    const int* ei_ji   = (const int*)d_in[5];
    const int* batch_i = (const int*)d_in[6];
    const int* batch_j = (const int*)d_in[7];
    const float* Wl0   = (const float*)d_in[8];
    const float* Wr0   = (const float*)d_in[9];
    const float* att0  = (const float*)d_in[10];
    const float* b0    = (const float*)d_in[11];
    const float* Wl1   = (const float*)d_in[12];
    const float* Wr1   = (const float*)d_in[13];
    const float* att1  = (const float*)d_in[14];
    const float* b1    = (const float*)d_in[15];
    const float* W_out = (const float*)d_in[16];
    const float* b_out = (const float*)d_in[17];
    const float* W_i   = (const float*)d_in[18];
    const float* b_i   = (const float*)d_in[19];
    const float* W_j   = (const float*)d_in[20];
    const float* b_j   = (const float*)d_in[21];
    float* out = (float*)d_out;

    // ---- workspace layout: ~31.5 MB (< 32 MiB) ----
    unsigned short* xl  = (unsigned short*)d_ws;            // [NN*CD] bf16   5,120,000 B
    unsigned short* xr  = xl + (size_t)NN * CD;             // [NN*CD] bf16   5,120,000 B
    float* acc          = (float*)(xr + (size_t)NN * CD);   // [NN*CD] f32   10,240,000 B
    unsigned short* z_i = (unsigned short*)(acc + (size_t)NN * CD); // bf16   5,120,000 B
    unsigned short* z_j = z_i + (size_t)NN * CD;            // [NN*CD] bf16   5,120,000 B
    unsigned short* pbuf= z_j + (size_t)NN * CD;            // [ETOT]  bf16     680,000 B
    float* sbuf         = (float*)(pbuf + (size_t)ETOT);    // [NN]    f32       80,000 B
    float* pool_i       = sbuf + NN;                        // [BG*CD] f32       32,768 B
    float* pool_j       = pool_i + BG * CD;                 // [BG*CD] f32       32,768 B

    const int fin_blocks = (NN * CD) / 256;

    // ======== layer 0 (K = 512, f32 node features) ========
    {   // group i: relations 0 (i->i) and 3 (j->i)
        const float* srcs[2] = { x_i, x_j };
        const float* dsts[2] = { x_i, x_i };
        const int* eis[2] = { ei_ii, ei_ji };
        const int rids[2] = { 0, 3 };
        run_group<float>(srcs, dsts, eis, rids, FD, Wl0, Wr0, att0,
                         xl, xr, pbuf, sbuf, acc, stream);
        finalize_kernel<<<fin_blocks, 256, 0, stream>>>(acc, b0 + 0 * HHD, b0 + 3 * HHD, z_i);
    }
    {   // group j: relations 1 (j->j) and 2 (i->j)
        const float* srcs[2] = { x_j, x_i };
        const float* dsts[2] = { x_j, x_j };
        const int* eis[2] = { ei_jj, ei_ij };
        const int rids[2] = { 1, 2 };
        run_group<float>(srcs, dsts, eis, rids, FD, Wl0, Wr0, att0,
                         xl, xr, pbuf, sbuf, acc, stream);
        finalize_kernel<<<fin_blocks, 256, 0, stream>>>(acc, b0 + 1 * HHD, b0 + 2 * HHD, z_j);
    }

    // ======== layer 1 (K = 128, bf16 internal z), finalize fused into pooling ========
    hipMemsetAsync(pool_i, 0, (size_t)BG * CD * sizeof(float), stream);
    hipMemsetAsync(pool_j, 0, (size_t)BG * CD * sizeof(float), stream);
    {   // group i
        const unsigned short* srcs[2] = { z_i, z_j };
        const unsigned short* dsts[2] = { z_i, z_i };
        const int* eis[2] = { ei_ii, ei_ji };
        const int rids[2] = { 0, 3 };
        run_group<unsigned short>(srcs, dsts, eis, rids, CD, Wl1, Wr1, att1,
                                  xl, xr, pbuf, sbuf, acc, stream);
        pool_fused_kernel<<<fin_blocks, 256, 0, stream>>>(acc, b1 + 0 * HHD, b1 + 3 * HHD,
                                                          batch_i, pool_i);
    }
    {   // group j
        const unsigned short* srcs[2] = { z_j, z_i };
        const unsigned short* dsts[2] = { z_j, z_j };
        const int* eis[2] = { ei_jj, ei_ij };
        const int rids[2] = { 1, 2 };
        run_group<unsigned short>(srcs, dsts, eis, rids, CD, Wl1, Wr1, att1,
                                  xl, xr, pbuf, sbuf, acc, stream);
        pool_fused_kernel<<<fin_blocks, 256, 0, stream>>>(acc, b1 + 1 * HHD, b1 + 2 * HHD,
                                                          batch_j, pool_j);
    }

    // ======== heads ========
    head_kernel<<<BG, 128, 0, stream>>>(pool_i, pool_j, W_out, b_out,
                                        W_i, b_i, W_j, b_j, out);
}

// Round 7
// 3183.921 us; speedup vs baseline: 4.8166x; 4.8166x over previous
//
#include <hip/hip_runtime.h>

// ---------------- problem constants ----------------
#define NN      20000     // nodes per type
#define EE      320000    // edges per relation
#define ETOT    340000    // EE + NN self loops
#define FD      512       // raw feature dim
#define HH_     4         // heads
#define CD      128       // channels per head
#define HHD     512       // H*C
#define BG      64        // batch graphs
#define INNERD  64

typedef __attribute__((ext_vector_type(8))) short bf16x8;
typedef __attribute__((ext_vector_type(4))) float f32x4;

// ---- bf16 <-> f32 via raw bits ----
__device__ __forceinline__ float bf2f(unsigned v) { return __uint_as_float(v << 16); }
__device__ __forceinline__ unsigned short f2bf(float f) {
    unsigned u = __float_as_uint(f);
    unsigned r = 0x7fffu + ((u >> 16) & 1u);
    return (unsigned short)((u + r) >> 16);
}
// split f32 -> hi + lo bf16 (16 mantissa bits total)
__device__ __forceinline__ void split_f32(float x, unsigned short& hi, unsigned short& lo) {
    hi = f2bf(x);
    lo = f2bf(x - bf2f(hi));
}
template <typename TA>
__device__ __forceinline__ void splitA(const TA* p, size_t i, unsigned short& hi, unsigned short& lo);
template <>
__device__ __forceinline__ void splitA<float>(const float* p, size_t i, unsigned short& hi, unsigned short& lo) {
    split_f32(p[i], hi, lo);
}
template <>
__device__ __forceinline__ void splitA<unsigned short>(const unsigned short* p, size_t i, unsigned short& hi, unsigned short& lo) {
    hi = p[i]; lo = 0;
}

// ================= CSR build (per relation, rebuilt every call) =================
__global__ __launch_bounds__(256) void csr_hist(const int* __restrict__ ei, int* __restrict__ cnt) {
    int e = blockIdx.x * blockDim.x + threadIdx.x;
    if (e < EE) atomicAdd(&cnt[ei[EE + e]], 1);
}

__global__ __launch_bounds__(1024) void csr_scan(const int* __restrict__ cnt,
                                                 int* __restrict__ rowptr,
                                                 int* __restrict__ cursor) {
    __shared__ int part[1024];
    int t = threadIdx.x;
    int base = t * 20;
    int s = 0;
    #pragma unroll
    for (int i = 0; i < 20; ++i) { int n = base + i; if (n < NN) s += cnt[n] + 1; }
    part[t] = s;
    __syncthreads();
    for (int off = 1; off < 1024; off <<= 1) {
        int v = (t >= off) ? part[t - off] : 0;
        __syncthreads();
        part[t] += v;
        __syncthreads();
    }
    int run = (t > 0) ? part[t - 1] : 0;
    #pragma unroll
    for (int i = 0; i < 20; ++i) {
        int n = base + i;
        if (n < NN) { rowptr[n] = run; cursor[n] = run; run += cnt[n] + 1; }
    }
    if (t == 1023) rowptr[NN] = run;
}

__global__ __launch_bounds__(256) void csr_scatter(const int* __restrict__ ei,
                                                   int* __restrict__ cursor,
                                                   int* __restrict__ srcs) {
    int idx = blockIdx.x * blockDim.x + threadIdx.x;
    if (idx >= ETOT) return;
    int src, dst;
    if (idx < EE) { src = ei[idx]; dst = ei[EE + idx]; }
    else          { src = dst = idx - EE; }
    int pos = atomicAdd(&cursor[dst], 1);
    srcs[pos] = src;
}

// ================= split-bf16 MFMA GEMM (near-f32 precision) =================
// C[M,128](bf16) = A[M,K] @ B[K, cols 0..127 of ldb](f32). 64x64 tile, 256 thr.
// A,B are hi/lo-split into bf16; D = Ah*Bh + Ah*Bl + (A_EXACT ? 0 : Al*Bh).
// blockIdx.z batches the xl / xr sides.
template <typename TA, bool A_EXACT>
__global__ __launch_bounds__(256) void gemm_mfma(
    const TA* __restrict__ A0, const TA* __restrict__ A1,
    const float* __restrict__ B0, const float* __restrict__ B1, int ldb,
    unsigned short* __restrict__ C0, unsigned short* __restrict__ C1,
    int M, int K)
{
    const TA* A = blockIdx.z ? A1 : A0;
    const float* B = blockIdx.z ? B1 : B0;
    unsigned short* C = blockIdx.z ? C1 : C0;

    __shared__ unsigned short Ah[64][40];   // [m][k] stride 80B; 16B-aligned segs
    __shared__ unsigned short Al[64][40];
    __shared__ unsigned short Bh[64][40];   // [n][k] (B transposed on store)
    __shared__ unsigned short Bl[64][40];
    const int tid = threadIdx.x;
    const int wave = tid >> 6, lane = tid & 63;
    const int quad = lane >> 4, lrow = lane & 15;
    const int tileM = blockIdx.y * 64, tileN = blockIdx.x * 64;
    const int wm = (wave >> 1) * 32, wn = (wave & 1) * 32;

    f32x4 acc[2][2] = {};

    const int am = tid >> 2;            // A loader: row (0..63)
    const int aks = (tid & 3) * 8;      // A loader: k-seg
    const int bn = tid & 63;            // B loader: col
    const int bk0 = (tid >> 6) * 8;     // B loader: k-seg

    for (int k0 = 0; k0 < K; k0 += 32) {
        // ---- stage A: 64 x 32, hi/lo split ----
        {
            int gm = tileM + am;
            bf16x8 ph = {}, pl = {};
            if (gm < M) {
                #pragma unroll
                for (int j = 0; j < 8; ++j) {
                    unsigned short h, l;
                    splitA(A, (size_t)gm * K + k0 + aks + j, h, l);
                    ph[j] = (short)h; pl[j] = (short)l;
                }
            }
            *reinterpret_cast<bf16x8*>(&Ah[am][aks]) = ph;
            if (!A_EXACT) *reinterpret_cast<bf16x8*>(&Al[am][aks]) = pl;
        }
        // ---- stage B (transposed): Bs[n][k], hi/lo split ----
        {
            bf16x8 ph, pl;
            #pragma unroll
            for (int j = 0; j < 8; ++j) {
                unsigned short h, l;
                split_f32(B[(size_t)(k0 + bk0 + j) * ldb + tileN + bn], h, l);
                ph[j] = (short)h; pl[j] = (short)l;
            }
            *reinterpret_cast<bf16x8*>(&Bh[bn][bk0]) = ph;
            *reinterpret_cast<bf16x8*>(&Bl[bn][bk0]) = pl;
        }
        __syncthreads();
        // ---- 2x2 MFMA 16x16x32 per wave, 3-term split product ----
        bf16x8 ah[2], al[2], bh[2], bl[2];
        #pragma unroll
        for (int mi = 0; mi < 2; ++mi) {
            ah[mi] = *reinterpret_cast<const bf16x8*>(&Ah[wm + mi * 16 + lrow][quad * 8]);
            if (!A_EXACT)
                al[mi] = *reinterpret_cast<const bf16x8*>(&Al[wm + mi * 16 + lrow][quad * 8]);
        }
        #pragma unroll
        for (int ni = 0; ni < 2; ++ni) {
            bh[ni] = *reinterpret_cast<const bf16x8*>(&Bh[wn + ni * 16 + lrow][quad * 8]);
            bl[ni] = *reinterpret_cast<const bf16x8*>(&Bl[wn + ni * 16 + lrow][quad * 8]);
        }
        #pragma unroll
        for (int mi = 0; mi < 2; ++mi)
            #pragma unroll
            for (int ni = 0; ni < 2; ++ni) {
                acc[mi][ni] = __builtin_amdgcn_mfma_f32_16x16x32_bf16(
                    ah[mi], bh[ni], acc[mi][ni], 0, 0, 0);
                acc[mi][ni] = __builtin_amdgcn_mfma_f32_16x16x32_bf16(
                    ah[mi], bl[ni], acc[mi][ni], 0, 0, 0);
                if (!A_EXACT)
                    acc[mi][ni] = __builtin_amdgcn_mfma_f32_16x16x32_bf16(
                        al[mi], bh[ni], acc[mi][ni], 0, 0, 0);
            }
        __syncthreads();
    }
    // ---- epilogue: C/D layout col=lane&15, row=quad*4+reg ----
    #pragma unroll
    for (int mi = 0; mi < 2; ++mi) {
        #pragma unroll
        for (int ni = 0; ni < 2; ++ni) {
            int gcol = tileN + wn + ni * 16 + lrow;
            #pragma unroll
            for (int r = 0; r < 4; ++r) {
                int grow = tileM + wm + mi * 16 + quad * 4 + r;
                if (grow < M)
                    C[(size_t)grow * CD + gcol] = f2bf(acc[mi][ni][r]);
            }
        }
    }
}

// ================= fused GATv2 edge pass: logits + softmax + aggregate =================
// one 64-lane wave per dst node; lane covers 2 of 128 channels.
__global__ __launch_bounds__(256) void fused_aggr(
    const int* __restrict__ rowptr, const int* __restrict__ srcs,
    const unsigned short* __restrict__ xl, const unsigned short* __restrict__ xr,
    const float* __restrict__ att,          // head slice [128] f32
    float* __restrict__ acc,                // [NN*CD] f32
    int add_in, int fin_mode,               // fin: 0 none, 1 z-write, 2 pool
    const float* __restrict__ bA, const float* __restrict__ bB,
    unsigned short* __restrict__ z,
    const int* __restrict__ batch, float* __restrict__ pool)
{
    int dst = (int)((blockIdx.x * (size_t)blockDim.x + threadIdx.x) >> 6);
    int lane = threadIdx.x & 63;
    if (dst >= NN) return;
    int beg = rowptr[dst], end = rowptr[dst + 1];

    unsigned ub = *reinterpret_cast<const unsigned*>(xr + (size_t)dst * CD + lane * 2);
    float br0 = bf2f(ub & 0xffffu), br1 = bf2f(ub >> 16);
    float ta0 = att[lane * 2], ta1 = att[lane * 2 + 1];

    float n0 = 0.f, n1 = 0.f, den = 0.f;
    for (int k = beg; k < end; ++k) {
        int src = srcs[k];
        unsigned ua = *reinterpret_cast<const unsigned*>(xl + (size_t)src * CD + lane * 2);
        float a0 = bf2f(ua & 0xffffu), a1 = bf2f(ua >> 16);
        float v0 = a0 + br0, v1 = a1 + br1;
        v0 = (v0 > 0.f) ? v0 : 0.2f * v0;
        v1 = (v1 > 0.f) ? v1 : 0.2f * v1;
        float d = v0 * ta0 + v1 * ta1;
        #pragma unroll
        for (int off = 1; off < 64; off <<= 1)
            d += __shfl_xor(d, off);
        float p = expf(d);                   // logits O(1); alpha invariant to max-shift
        n0 += p * a0; n1 += p * a1; den += p;
    }
    float o0 = n0 / den, o1 = n1 / den;      // den >= self-loop term > 0
    size_t ai = (size_t)dst * CD + lane * 2;
    if (add_in) { o0 += acc[ai]; o1 += acc[ai + 1]; }
    if (fin_mode == 0) {
        acc[ai] = o0; acc[ai + 1] = o1;
    } else {
        int c0 = lane * 2;
        float bb0 = 0.f, bb1 = 0.f;
        #pragma unroll
        for (int h = 0; h < HH_; ++h) {
            bb0 += bA[h * CD + c0]     + bB[h * CD + c0];
            bb1 += bA[h * CD + c0 + 1] + bB[h * CD + c0 + 1];
        }
        o0 = tanhf(o0 + bb0);
        o1 = tanhf(o1 + bb1);
        if (fin_mode == 1) {
            z[ai] = f2bf(o0); z[ai + 1] = f2bf(o1);
        } else {
            int b = batch[dst];
            atomicAdd(&pool[(size_t)b * CD + c0],     o0);
            atomicAdd(&pool[(size_t)b * CD + c0 + 1], o1);
        }
    }
}

// ================= head: tanh(pool), small GEMVs, sigmoid; f32 out =================
__global__ __launch_bounds__(128) void head_kernel(
    const float* __restrict__ pool_i, const float* __restrict__ pool_j,
    const float* __restrict__ W_out, const float* __restrict__ b_out,
    const float* __restrict__ W_i, const float* __restrict__ b_i,
    const float* __restrict__ W_j, const float* __restrict__ b_j,
    float* __restrict__ out)
{
    int b = blockIdx.x;
    int t = threadIdx.x;
    __shared__ float pi[CD], pj[CD];
    pi[t] = tanhf(pool_i[(size_t)b * CD + t]);
    pj[t] = tanhf(pool_j[(size_t)b * CD + t]);
    __syncthreads();
    if (t < INNERD) {
        float a = b_i[t];
        for (int c = 0; c < CD; ++c) a += pi[c] * W_i[c * INNERD + t];
        out[BG + (size_t)b * INNERD + t] = a;
    } else {
        int k = t - INNERD;
        float a = b_j[k];
        for (int c = 0; c < CD; ++c) a += pj[c] * W_j[c * INNERD + k];
        out[BG + BG * INNERD + (size_t)b * INNERD + k] = a;
    }
    if (t == 0) {
        float a = b_out[0];
        for (int c = 0; c < CD; ++c) a += (pi[c] + pj[c]) * W_out[c];
        out[b] = 1.f / (1.f + expf(-a));
    }
}

// ================= host-side drivers =================
struct Ws {
    unsigned short *xl, *xr, *z_i, *z_j;
    float* acc;
    int *rowptr, *cnt, *cursor, *srcs;
    float *pool_i, *pool_j;
};

static void build_csr(const int* ei, const Ws& w, hipStream_t stream) {
    hipMemsetAsync(w.cnt, 0, NN * sizeof(int), stream);
    csr_hist<<<(EE + 255) / 256, 256, 0, stream>>>(ei, w.cnt);
    csr_scan<<<1, 1024, 0, stream>>>(w.cnt, w.rowptr, w.cursor);
    csr_scatter<<<(ETOT + 255) / 256, 256, 0, stream>>>(ei, w.cursor, w.srcs);
}

template <typename TA, bool A_EXACT>
static void run_group(const TA* srcA[2], const TA* dstA[2],
                      const int* eis[2], const int rids[2], int K,
                      const float* Wl, const float* Wr, const float* att,
                      const float* bias,
                      int fin_mode,                // 1: z write, 2: pool
                      unsigned short* zout, const int* batch, float* pool,
                      const Ws& w, hipStream_t stream)
{
    dim3 gg(2, (NN + 63) / 64, 2);
    const int ablocks = NN / 4;   // 4 dst-waves per 256-thread block
    for (int q = 0; q < 2; ++q) {
        int r = rids[q];
        build_csr(eis[q], w, stream);
        for (int h = 0; h < HH_; ++h) {
            const float* WlS = Wl + (size_t)r * K * HHD + h * CD;
            const float* WrS = Wr + (size_t)r * K * HHD + h * CD;
            gemm_mfma<TA, A_EXACT><<<gg, 256, 0, stream>>>(
                srcA[q], dstA[q], WlS, WrS, HHD, w.xl, w.xr, NN, K);
            int pass = q * HH_ + h;
            int fm = (pass == 2 * HH_ - 1) ? fin_mode : 0;
            fused_aggr<<<ablocks, 256, 0, stream>>>(
                w.rowptr, w.srcs, w.xl, w.xr,
                att + (size_t)r * HHD + h * CD,
                w.acc, pass > 0 ? 1 : 0, fm,
                bias + (size_t)rids[0] * HHD, bias + (size_t)rids[1] * HHD,
                zout, batch, pool);
        }
    }
}

extern "C" void kernel_launch(void* const* d_in, const int* in_sizes, int n_in,
                              void* d_out, int out_size, void* d_ws, size_t ws_size,
                              hipStream_t stream)
{
    const float* x_i   = (const float*)d_in[0];
    const float* x_j   = (const float*)d_in[1];
    const int* ei_ii   = (const int*)d_in[2];
    const int* ei_jj   = (const int*)d_in[3];
    const int* ei_ij   = (const int*)d_in[4];
    const int* ei_ji   = (const int*)d_in[5];
    const int* batch_i = (const int*)d_in[6];
    const int* batch_j = (const int*)d_in[7];
    const float* Wl0   = (const float*)d_in[8];
    const float* Wr0   = (const float*)d_in[9];
    const float* att0  = (const float*)d_in[10];
    const float* b0    = (const float*)d_in[11];
    const float* Wl1   = (const float*)d_in[12];
    const float* Wr1   = (const float*)d_in[13];
    const float* att1  = (const float*)d_in[14];
    const float* b1    = (const float*)d_in[15];
    const float* W_out = (const float*)d_in[16];
    const float* b_out = (const float*)d_in[17];
    const float* W_i   = (const float*)d_in[18];
    const float* b_i   = (const float*)d_in[19];
    const float* W_j   = (const float*)d_in[20];
    const float* b_j   = (const float*)d_in[21];
    float* out = (float*)d_out;

    // ---- workspace layout: ~32.4 MB ----
    Ws w;
    char* p = (char*)d_ws;
    w.xl     = (unsigned short*)p; p += (size_t)NN * CD * 2;   //  5,120,000
    w.xr     = (unsigned short*)p; p += (size_t)NN * CD * 2;   //  5,120,000
    w.z_i    = (unsigned short*)p; p += (size_t)NN * CD * 2;   //  5,120,000
    w.z_j    = (unsigned short*)p; p += (size_t)NN * CD * 2;   //  5,120,000
    w.acc    = (float*)p;          p += (size_t)NN * CD * 4;   // 10,240,000
    w.rowptr = (int*)p;            p += (NN + 4) * 4;          //     80,016
    w.cnt    = (int*)p;            p += NN * 4;                //     80,000
    w.cursor = (int*)p;            p += NN * 4;                //     80,000
    w.srcs   = (int*)p;            p += (size_t)ETOT * 4;      //  1,360,000
    w.pool_i = (float*)p;          p += BG * CD * 4;           //     32,768
    w.pool_j = (float*)p;          p += BG * CD * 4;           //     32,768

    // ======== layer 0 (K=512, f32 node features) ========
    {   // group i: rel 0 (x_i->x_i, ei_ii), rel 3 (x_j->x_i, ei_ji) -> z_i
        const float* srcA[2] = { x_i, x_j };
        const float* dstA[2] = { x_i, x_i };
        const int* eis[2] = { ei_ii, ei_ji };
        const int rids[2] = { 0, 3 };
        run_group<float, false>(srcA, dstA, eis, rids, FD, Wl0, Wr0, att0, b0,
                                1, w.z_i, nullptr, nullptr, w, stream);
    }
    {   // group j: rel 1 (x_j->x_j, ei_jj), rel 2 (x_i->x_j, ei_ij) -> z_j
        const float* srcA[2] = { x_j, x_i };
        const float* dstA[2] = { x_j, x_j };
        const int* eis[2] = { ei_jj, ei_ij };
        const int rids[2] = { 1, 2 };
        run_group<float, false>(srcA, dstA, eis, rids, FD, Wl0, Wr0, att0, b0,
                                1, w.z_j, nullptr, nullptr, w, stream);
    }

    // ======== layer 1 (K=128, bf16 z — exact A), finalize fused into pooling ========
    hipMemsetAsync(w.pool_i, 0, (size_t)BG * CD * sizeof(float), stream);
    hipMemsetAsync(w.pool_j, 0, (size_t)BG * CD * sizeof(float), stream);
    {   // group i -> pool_i
        const unsigned short* srcA[2] = { w.z_i, w.z_j };
        const unsigned short* dstA[2] = { w.z_i, w.z_i };
        const int* eis[2] = { ei_ii, ei_ji };
        const int rids[2] = { 0, 3 };
        run_group<unsigned short, true>(srcA, dstA, eis, rids, CD, Wl1, Wr1, att1, b1,
                                        2, nullptr, batch_i, w.pool_i, w, stream);
    }
    {   // group j -> pool_j
        const unsigned short* srcA[2] = { w.z_j, w.z_i };
        const unsigned short* dstA[2] = { w.z_j, w.z_j };
        const int* eis[2] = { ei_jj, ei_ij };
        const int rids[2] = { 1, 2 };
        run_group<unsigned short, true>(srcA, dstA, eis, rids, CD, Wl1, Wr1, att1, b1,
                                        2, nullptr, batch_j, w.pool_j, w, stream);
    }

    // ======== heads ========
    head_kernel<<<BG, 128, 0, stream>>>(w.pool_i, w.pool_j, W_out, b_out,
                                        W_i, b_i, W_j, b_j, out);
}

// Round 8
// 2252.984 us; speedup vs baseline: 6.8068x; 1.4132x over previous
//
#include <hip/hip_runtime.h>

// ---------------- problem constants ----------------
#define NN      20000     // nodes per type
#define EE      320000    // edges per relation
#define ETOT    340000    // EE + NN self loops
#define FD      512      // raw feature dim
#define HH_     4         // heads
#define CD      128       // channels per head
#define HHD     512       // H*C
#define BG      64        // batch graphs
#define INNERD  64

typedef __attribute__((ext_vector_type(8))) short bf16x8;
typedef __attribute__((ext_vector_type(4))) float f32x4;

// ---- bf16 <-> f32 via raw bits ----
__device__ __forceinline__ float bf2f(unsigned v) { return __uint_as_float(v << 16); }
__device__ __forceinline__ unsigned short f2bf(float f) {
    unsigned u = __float_as_uint(f);
    unsigned r = 0x7fffu + ((u >> 16) & 1u);
    return (unsigned short)((u + r) >> 16);
}
__device__ __forceinline__ void load8bf(const unsigned short* p, float* f) {
    uint4 u = *reinterpret_cast<const uint4*>(p);
    f[0] = bf2f(u.x & 0xffffu); f[1] = bf2f(u.x >> 16);
    f[2] = bf2f(u.y & 0xffffu); f[3] = bf2f(u.y >> 16);
    f[4] = bf2f(u.z & 0xffffu); f[5] = bf2f(u.z >> 16);
    f[6] = bf2f(u.w & 0xffffu); f[7] = bf2f(u.w >> 16);
}
// split f32 -> hi + lo bf16 (16 mantissa bits total)
__device__ __forceinline__ void split_f32(float x, unsigned short& hi, unsigned short& lo) {
    hi = f2bf(x);
    lo = f2bf(x - bf2f(hi));
}
template <typename TA>
__device__ __forceinline__ void splitA(const TA* p, size_t i, unsigned short& hi, unsigned short& lo);
template <>
__device__ __forceinline__ void splitA<float>(const float* p, size_t i, unsigned short& hi, unsigned short& lo) {
    split_f32(p[i], hi, lo);
}
template <>
__device__ __forceinline__ void splitA<unsigned short>(const unsigned short* p, size_t i, unsigned short& hi, unsigned short& lo) {
    hi = p[i]; lo = 0;
}

// ================= CSR build (per relation, rebuilt every call) =================
__global__ __launch_bounds__(256) void csr_hist(const int* __restrict__ ei, int* __restrict__ cnt) {
    int e = blockIdx.x * blockDim.x + threadIdx.x;
    if (e < EE) atomicAdd(&cnt[ei[EE + e]], 1);
}

__global__ __launch_bounds__(1024) void csr_scan(const int* __restrict__ cnt,
                                                 int* __restrict__ rowptr,
                                                 int* __restrict__ cursor) {
    __shared__ int part[1024];
    int t = threadIdx.x;
    int base = t * 20;
    int s = 0;
    #pragma unroll
    for (int i = 0; i < 20; ++i) { int n = base + i; if (n < NN) s += cnt[n] + 1; }
    part[t] = s;
    __syncthreads();
    for (int off = 1; off < 1024; off <<= 1) {
        int v = (t >= off) ? part[t - off] : 0;
        __syncthreads();
        part[t] += v;
        __syncthreads();
    }
    int run = (t > 0) ? part[t - 1] : 0;
    #pragma unroll
    for (int i = 0; i < 20; ++i) {
        int n = base + i;
        if (n < NN) { rowptr[n] = run; cursor[n] = run; run += cnt[n] + 1; }
    }
    if (t == 1023) rowptr[NN] = run;
}

__global__ __launch_bounds__(256) void csr_scatter(const int* __restrict__ ei,
                                                   int* __restrict__ cursor,
                                                   int* __restrict__ srcs) {
    int idx = blockIdx.x * blockDim.x + threadIdx.x;
    if (idx >= ETOT) return;
    int src, dst;
    if (idx < EE) { src = ei[idx]; dst = ei[EE + idx]; }
    else          { src = dst = idx - EE; }
    int pos = atomicAdd(&cursor[dst], 1);
    srcs[pos] = src;
}

// ================= split-bf16 MFMA GEMM (near-f32 precision) =================
// C[M,N](bf16) = A[M,K] @ B[K, N cols of ldb](f32). 64x64 tiles, 256 thr.
// D = Ah*Bh + Ah*Bl + (A_EXACT ? 0 : Al*Bh). blockIdx.z batches xl / xr sides.
template <typename TA, bool A_EXACT>
__global__ __launch_bounds__(256) void gemm_mfma(
    const TA* __restrict__ A0, const TA* __restrict__ A1,
    const float* __restrict__ B0, const float* __restrict__ B1, int ldb,
    unsigned short* __restrict__ C0, unsigned short* __restrict__ C1,
    int M, int K, int N)
{
    const TA* A = blockIdx.z ? A1 : A0;
    const float* B = blockIdx.z ? B1 : B0;
    unsigned short* C = blockIdx.z ? C1 : C0;

    __shared__ unsigned short Ah[64][40];   // [m][k] stride 80B; 16B-aligned segs
    __shared__ unsigned short Al[64][40];
    __shared__ unsigned short Bh[64][40];   // [n][k] (B transposed on store)
    __shared__ unsigned short Bl[64][40];
    const int tid = threadIdx.x;
    const int wave = tid >> 6, lane = tid & 63;
    const int quad = lane >> 4, lrow = lane & 15;
    const int tileM = blockIdx.y * 64, tileN = blockIdx.x * 64;
    const int wm = (wave >> 1) * 32, wn = (wave & 1) * 32;

    f32x4 acc[2][2] = {};

    const int am = tid >> 2;            // A loader: row (0..63)
    const int aks = (tid & 3) * 8;      // A loader: k-seg
    const int bn = tid & 63;            // B loader: col
    const int bk0 = (tid >> 6) * 8;     // B loader: k-seg

    for (int k0 = 0; k0 < K; k0 += 32) {
        {   // ---- stage A: 64 x 32, hi/lo split ----
            int gm = tileM + am;
            bf16x8 ph = {}, pl = {};
            if (gm < M) {
                #pragma unroll
                for (int j = 0; j < 8; ++j) {
                    unsigned short h, l;
                    splitA(A, (size_t)gm * K + k0 + aks + j, h, l);
                    ph[j] = (short)h; pl[j] = (short)l;
                }
            }
            *reinterpret_cast<bf16x8*>(&Ah[am][aks]) = ph;
            if (!A_EXACT) *reinterpret_cast<bf16x8*>(&Al[am][aks]) = pl;
        }
        {   // ---- stage B (transposed): Bs[n][k], hi/lo split ----
            bf16x8 ph, pl;
            #pragma unroll
            for (int j = 0; j < 8; ++j) {
                unsigned short h, l;
                split_f32(B[(size_t)(k0 + bk0 + j) * ldb + tileN + bn], h, l);
                ph[j] = (short)h; pl[j] = (short)l;
            }
            *reinterpret_cast<bf16x8*>(&Bh[bn][bk0]) = ph;
            *reinterpret_cast<bf16x8*>(&Bl[bn][bk0]) = pl;
        }
        __syncthreads();
        bf16x8 ah[2], al[2], bh[2], bl[2];
        #pragma unroll
        for (int mi = 0; mi < 2; ++mi) {
            ah[mi] = *reinterpret_cast<const bf16x8*>(&Ah[wm + mi * 16 + lrow][quad * 8]);
            if (!A_EXACT)
                al[mi] = *reinterpret_cast<const bf16x8*>(&Al[wm + mi * 16 + lrow][quad * 8]);
        }
        #pragma unroll
        for (int ni = 0; ni < 2; ++ni) {
            bh[ni] = *reinterpret_cast<const bf16x8*>(&Bh[wn + ni * 16 + lrow][quad * 8]);
            bl[ni] = *reinterpret_cast<const bf16x8*>(&Bl[wn + ni * 16 + lrow][quad * 8]);
        }
        #pragma unroll
        for (int mi = 0; mi < 2; ++mi)
            #pragma unroll
            for (int ni = 0; ni < 2; ++ni) {
                acc[mi][ni] = __builtin_amdgcn_mfma_f32_16x16x32_bf16(
                    ah[mi], bh[ni], acc[mi][ni], 0, 0, 0);
                acc[mi][ni] = __builtin_amdgcn_mfma_f32_16x16x32_bf16(
                    ah[mi], bl[ni], acc[mi][ni], 0, 0, 0);
                if (!A_EXACT)
                    acc[mi][ni] = __builtin_amdgcn_mfma_f32_16x16x32_bf16(
                        al[mi], bh[ni], acc[mi][ni], 0, 0, 0);
            }
        __syncthreads();
    }
    // ---- epilogue: C/D layout col=lane&15, row=quad*4+reg ----
    #pragma unroll
    for (int mi = 0; mi < 2; ++mi) {
        #pragma unroll
        for (int ni = 0; ni < 2; ++ni) {
            int gcol = tileN + wn + ni * 16 + lrow;
            #pragma unroll
            for (int r = 0; r < 4; ++r) {
                int grow = tileM + wm + mi * 16 + quad * 4 + r;
                if (grow < M)
                    C[(size_t)grow * N + gcol] = f2bf(acc[mi][ni][r]);
            }
        }
    }
}

// ================= THIN: fused GATv2 pass, one head (xl/xr [NN,128]) =================
__global__ __launch_bounds__(256) void fused_aggr1(
    const int* __restrict__ rowptr, const int* __restrict__ srcs,
    const unsigned short* __restrict__ xl, const unsigned short* __restrict__ xr,
    const float* __restrict__ att,
    float* __restrict__ acc, int add_in, int fin_mode,
    const float* __restrict__ bA, const float* __restrict__ bB,
    unsigned short* __restrict__ z,
    const int* __restrict__ batch, float* __restrict__ pool)
{
    int dst = (int)((blockIdx.x * (size_t)blockDim.x + threadIdx.x) >> 6);
    int lane = threadIdx.x & 63;
    if (dst >= NN) return;
    int beg = rowptr[dst], end = rowptr[dst + 1];

    unsigned ub = *reinterpret_cast<const unsigned*>(xr + (size_t)dst * CD + lane * 2);
    float br0 = bf2f(ub & 0xffffu), br1 = bf2f(ub >> 16);
    float ta0 = att[lane * 2], ta1 = att[lane * 2 + 1];

    float n0 = 0.f, n1 = 0.f, den = 0.f;
    for (int k = beg; k < end; ++k) {
        int src = srcs[k];
        unsigned ua = *reinterpret_cast<const unsigned*>(xl + (size_t)src * CD + lane * 2);
        float a0 = bf2f(ua & 0xffffu), a1 = bf2f(ua >> 16);
        float v0 = a0 + br0, v1 = a1 + br1;
        v0 = (v0 > 0.f) ? v0 : 0.2f * v0;
        v1 = (v1 > 0.f) ? v1 : 0.2f * v1;
        float d = v0 * ta0 + v1 * ta1;
        #pragma unroll
        for (int off = 1; off < 64; off <<= 1)
            d += __shfl_xor(d, off);
        float p = expf(d);
        n0 += p * a0; n1 += p * a1; den += p;
    }
    float o0 = n0 / den, o1 = n1 / den;
    size_t ai = (size_t)dst * CD + lane * 2;
    if (add_in) { o0 += acc[ai]; o1 += acc[ai + 1]; }
    if (fin_mode == 0) {
        acc[ai] = o0; acc[ai + 1] = o1;
    } else {
        int c0 = lane * 2;
        float bb0 = 0.f, bb1 = 0.f;
        #pragma unroll
        for (int h = 0; h < HH_; ++h) {
            bb0 += bA[h * CD + c0]     + bB[h * CD + c0];
            bb1 += bA[h * CD + c0 + 1] + bB[h * CD + c0 + 1];
        }
        o0 = tanhf(o0 + bb0);
        o1 = tanhf(o1 + bb1);
        if (fin_mode == 1) {
            z[ai] = f2bf(o0); z[ai + 1] = f2bf(o1);
        } else {
            int b = batch[dst];
            atomicAdd(&pool[(size_t)b * CD + c0],     o0);
            atomicAdd(&pool[(size_t)b * CD + c0 + 1], o1);
        }
    }
}

// ================= FAT: fused GATv2 pass, ALL 4 heads (xl/xr [NN,512]) =================
// one 64-lane wave per dst; 16-lane group per head; lane holds 8 channels (16B loads).
// Per-edge reduce uses only xor 1/2/4/8 (fast row DPP); head-sum xor16/32 once per dst.
__global__ __launch_bounds__(256) void fused_aggr4(
    const int* __restrict__ rowptr, const int* __restrict__ srcs,
    const unsigned short* __restrict__ xl, const unsigned short* __restrict__ xr,
    const float* __restrict__ att,          // [512] f32 this relation (all heads)
    float* __restrict__ acc, int add_in, int fin_mode,
    const float* __restrict__ bA, const float* __restrict__ bB,
    unsigned short* __restrict__ z,
    const int* __restrict__ batch, float* __restrict__ pool)
{
    int dst = (int)((blockIdx.x * (size_t)blockDim.x + threadIdx.x) >> 6);
    int lane = threadIdx.x & 63;
    if (dst >= NN) return;
    int beg = rowptr[dst], end = rowptr[dst + 1];

    float br[8], ta[8];
    load8bf(xr + (size_t)dst * HHD + lane * 8, br);
    #pragma unroll
    for (int j = 0; j < 8; ++j) ta[j] = att[lane * 8 + j];

    float n[8] = {}; float den = 0.f;
    for (int k = beg; k < end; ++k) {
        int src = srcs[k];
        float a[8];
        load8bf(xl + (size_t)src * HHD + lane * 8, a);
        float d = 0.f;
        #pragma unroll
        for (int j = 0; j < 8; ++j) {
            float v = a[j] + br[j];
            v = (v > 0.f) ? v : 0.2f * v;
            d += v * ta[j];
        }
        d += __shfl_xor(d, 1);
        d += __shfl_xor(d, 2);
        d += __shfl_xor(d, 4);
        d += __shfl_xor(d, 8);
        float p = expf(d);
        den += p;
        #pragma unroll
        for (int j = 0; j < 8; ++j) n[j] += p * a[j];
    }
    float inv = 1.f / den;
    float o[8];
    #pragma unroll
    for (int j = 0; j < 8; ++j) {
        o[j] = n[j] * inv;
        o[j] += __shfl_xor(o[j], 16);   // head-sum (once per dst)
        o[j] += __shfl_xor(o[j], 32);
    }
    if (lane < 16) {
        size_t ai = (size_t)dst * CD + lane * 8;
        if (add_in) {
            #pragma unroll
            for (int j = 0; j < 8; ++j) o[j] += acc[ai + j];
        }
        if (fin_mode == 0) {
            #pragma unroll
            for (int j = 0; j < 8; ++j) acc[ai + j] = o[j];
        } else {
            int c0 = lane * 8;
            #pragma unroll
            for (int j = 0; j < 8; ++j) {
                float bb = 0.f;
                #pragma unroll
                for (int h = 0; h < HH_; ++h)
                    bb += bA[h * CD + c0 + j] + bB[h * CD + c0 + j];
                o[j] = tanhf(o[j] + bb);
            }
            if (fin_mode == 1) {
                #pragma unroll
                for (int j = 0; j < 8; ++j) z[ai + j] = f2bf(o[j]);
            } else {
                int b = batch[dst];
                #pragma unroll
                for (int j = 0; j < 8; ++j)
                    atomicAdd(&pool[(size_t)b * CD + c0 + j], o[j]);
            }
        }
    }
}

// ================= head: tanh(pool), small GEMVs, sigmoid; f32 out =================
__global__ __launch_bounds__(128) void head_kernel(
    const float* __restrict__ pool_i, const float* __restrict__ pool_j,
    const float* __restrict__ W_out, const float* __restrict__ b_out,
    const float* __restrict__ W_i, const float* __restrict__ b_i,
    const float* __restrict__ W_j, const float* __restrict__ b_j,
    float* __restrict__ out)
{
    int b = blockIdx.x;
    int t = threadIdx.x;
    __shared__ float pi[CD], pj[CD];
    pi[t] = tanhf(pool_i[(size_t)b * CD + t]);
    pj[t] = tanhf(pool_j[(size_t)b * CD + t]);
    __syncthreads();
    if (t < INNERD) {
        float a = b_i[t];
        for (int c = 0; c < CD; ++c) a += pi[c] * W_i[c * INNERD + t];
        out[BG + (size_t)b * INNERD + t] = a;
    } else {
        int k = t - INNERD;
        float a = b_j[k];
        for (int c = 0; c < CD; ++c) a += pj[c] * W_j[c * INNERD + k];
        out[BG + BG * INNERD + (size_t)b * INNERD + k] = a;
    }
    if (t == 0) {
        float a = b_out[0];
        for (int c = 0; c < CD; ++c) a += (pi[c] + pj[c]) * W_out[c];
        out[b] = 1.f / (1.f + expf(-a));
    }
}

// ================= host-side drivers =================
struct Ws {
    unsigned short *xl, *xr, *z_i, *z_j;
    float* acc;
    int *rowptr, *cnt, *cursor, *srcs;
    float *pool_i, *pool_j;
};

static void build_csr(const int* ei, const Ws& w, hipStream_t stream) {
    hipMemsetAsync(w.cnt, 0, NN * sizeof(int), stream);
    csr_hist<<<(EE + 255) / 256, 256, 0, stream>>>(ei, w.cnt);
    csr_scan<<<1, 1024, 0, stream>>>(w.cnt, w.rowptr, w.cursor);
    csr_scatter<<<(ETOT + 255) / 256, 256, 0, stream>>>(ei, w.cursor, w.srcs);
}

// ---- THIN path: per-head passes (xl/xr [NN,128]) ----
template <typename TA, bool A_EXACT>
static void run_group_thin(const TA* srcA[2], const TA* dstA[2],
                           const int* eis[2], const int rids[2], int K,
                           const float* Wl, const float* Wr, const float* att,
                           const float* bias, int fin_mode,
                           unsigned short* zout, const int* batch, float* pool,
                           const Ws& w, hipStream_t stream)
{
    dim3 gg(2, (NN + 63) / 64, 2);
    const int ablocks = NN / 4;
    for (int q = 0; q < 2; ++q) {
        int r = rids[q];
        build_csr(eis[q], w, stream);
        for (int h = 0; h < HH_; ++h) {
            const float* WlS = Wl + (size_t)r * K * HHD + h * CD;
            const float* WrS = Wr + (size_t)r * K * HHD + h * CD;
            gemm_mfma<TA, A_EXACT><<<gg, 256, 0, stream>>>(
                srcA[q], dstA[q], WlS, WrS, HHD, w.xl, w.xr, NN, K, CD);
            int pass = q * HH_ + h;
            int fm = (pass == 2 * HH_ - 1) ? fin_mode : 0;
            fused_aggr1<<<ablocks, 256, 0, stream>>>(
                w.rowptr, w.srcs, w.xl, w.xr,
                att + (size_t)r * HHD + h * CD,
                w.acc, pass > 0 ? 1 : 0, fm,
                bias + (size_t)rids[0] * HHD, bias + (size_t)rids[1] * HHD,
                zout, batch, pool);
        }
    }
}

// ---- FAT path: all-heads passes (xl/xr [NN,512]) ----
template <typename TA, bool A_EXACT>
static void run_group_fat(const TA* srcA[2], const TA* dstA[2],
                          const int* eis[2], const int rids[2], int K,
                          const float* Wl, const float* Wr, const float* att,
                          const float* bias, int fin_mode,
                          unsigned short* zout, const int* batch, float* pool,
                          const Ws& w, hipStream_t stream)
{
    dim3 gg(HHD / 64, (NN + 63) / 64, 2);
    const int ablocks = NN / 4;
    for (int q = 0; q < 2; ++q) {
        int r = rids[q];
        build_csr(eis[q], w, stream);
        gemm_mfma<TA, A_EXACT><<<gg, 256, 0, stream>>>(
            srcA[q], dstA[q],
            Wl + (size_t)r * K * HHD, Wr + (size_t)r * K * HHD, HHD,
            w.xl, w.xr, NN, K, HHD);
        int fm = (q == 1) ? fin_mode : 0;
        fused_aggr4<<<ablocks, 256, 0, stream>>>(
            w.rowptr, w.srcs, w.xl, w.xr,
            att + (size_t)r * HHD,
            w.acc, q > 0 ? 1 : 0, fm,
            bias + (size_t)rids[0] * HHD, bias + (size_t)rids[1] * HHD,
            zout, batch, pool);
    }
}

extern "C" void kernel_launch(void* const* d_in, const int* in_sizes, int n_in,
                              void* d_out, int out_size, void* d_ws, size_t ws_size,
                              hipStream_t stream)
{
    const float* x_i   = (const float*)d_in[0];
    const float* x_j   = (const float*)d_in[1];
    const int* ei_ii   = (const int*)d_in[2];
    const int* ei_jj   = (const int*)d_in[3];
    const int* ei_ij   = (const int*)d_in[4];
    const int* ei_ji   = (const int*)d_in[5];
    const int* batch_i = (const int*)d_in[6];
    const int* batch_j = (const int*)d_in[7];
    const float* Wl0   = (const float*)d_in[8];
    const float* Wr0   = (const float*)d_in[9];
    const float* att0  = (const float*)d_in[10];
    const float* b0    = (const float*)d_in[11];
    const float* Wl1   = (const float*)d_in[12];
    const float* Wr1   = (const float*)d_in[13];
    const float* att1  = (const float*)d_in[14];
    const float* b1    = (const float*)d_in[15];
    const float* W_out = (const float*)d_in[16];
    const float* b_out = (const float*)d_in[17];
    const float* W_i   = (const float*)d_in[18];
    const float* b_i   = (const float*)d_in[19];
    const float* W_j   = (const float*)d_in[20];
    const float* b_j   = (const float*)d_in[21];
    float* out = (float*)d_out;

    // FAT needs: xl,xr [NN,512]bf16 + acc [NN,128]f32 + z_i,z_j [NN,128]bf16 + CSR + pools
    const size_t FAT_BYTES = (size_t)NN * HHD * 2 * 2      // xl, xr
                           + (size_t)NN * CD * 4           // acc
                           + (size_t)NN * CD * 2 * 2       // z_i, z_j
                           + (size_t)(NN + 4) * 4          // rowptr
                           + (size_t)NN * 4 * 2            // cnt, cursor
                           + (size_t)ETOT * 4              // srcs
                           + (size_t)BG * CD * 4 * 2;      // pools   = 63,105,552
    const bool fat = (ws_size >= FAT_BYTES);

    Ws w;
    char* p = (char*)d_ws;
    size_t xbytes = fat ? (size_t)NN * HHD * 2 : (size_t)NN * CD * 2;
    w.xl     = (unsigned short*)p; p += xbytes;
    w.xr     = (unsigned short*)p; p += xbytes;
    w.acc    = (float*)p;          p += (size_t)NN * CD * 4;
    w.z_i    = (unsigned short*)p; p += (size_t)NN * CD * 2;
    w.z_j    = (unsigned short*)p; p += (size_t)NN * CD * 2;
    w.rowptr = (int*)p;            p += (size_t)(NN + 4) * 4;
    w.cnt    = (int*)p;            p += (size_t)NN * 4;
    w.cursor = (int*)p;            p += (size_t)NN * 4;
    w.srcs   = (int*)p;            p += (size_t)ETOT * 4;
    w.pool_i = (float*)p;          p += (size_t)BG * CD * 4;
    w.pool_j = (float*)p;          p += (size_t)BG * CD * 4;

    hipMemsetAsync(w.pool_i, 0, (size_t)BG * CD * sizeof(float), stream);
    hipMemsetAsync(w.pool_j, 0, (size_t)BG * CD * sizeof(float), stream);

    // relation groups:  i <- {rel0: ii, rel3: ji},  j <- {rel1: jj, rel2: ij}
    const float* srcA0_i[2] = { x_i, x_j };  const float* dstA0_i[2] = { x_i, x_i };
    const float* srcA0_j[2] = { x_j, x_i };  const float* dstA0_j[2] = { x_j, x_j };
    const int* eis_i[2] = { ei_ii, ei_ji };  const int rids_i[2] = { 0, 3 };
    const int* eis_j[2] = { ei_jj, ei_ij };  const int rids_j[2] = { 1, 2 };
    const unsigned short* srcA1_i[2] = { w.z_i, w.z_j };
    const unsigned short* dstA1_i[2] = { w.z_i, w.z_i };
    const unsigned short* srcA1_j[2] = { w.z_j, w.z_i };
    const unsigned short* dstA1_j[2] = { w.z_j, w.z_j };

    if (fat) {
        run_group_fat<float, false>(srcA0_i, dstA0_i, eis_i, rids_i, FD, Wl0, Wr0, att0, b0,
                                    1, w.z_i, nullptr, nullptr, w, stream);
        run_group_fat<float, false>(srcA0_j, dstA0_j, eis_j, rids_j, FD, Wl0, Wr0, att0, b0,
                                    1, w.z_j, nullptr, nullptr, w, stream);
        run_group_fat<unsigned short, true>(srcA1_i, dstA1_i, eis_i, rids_i, CD, Wl1, Wr1, att1, b1,
                                            2, nullptr, batch_i, w.pool_i, w, stream);
        run_group_fat<unsigned short, true>(srcA1_j, dstA1_j, eis_j, rids_j, CD, Wl1, Wr1, att1, b1,
                                            2, nullptr, batch_j, w.pool_j, w, stream);
    } else {
        run_group_thin<float, false>(srcA0_i, dstA0_i, eis_i, rids_i, FD, Wl0, Wr0, att0, b0,
                                     1, w.z_i, nullptr, nullptr, w, stream);
        run_group_thin<float, false>(srcA0_j, dstA0_j, eis_j, rids_j, FD, Wl0, Wr0, att0, b0,
                                     1, w.z_j, nullptr, nullptr, w, stream);
        run_group_thin<unsigned short, true>(srcA1_i, dstA1_i, eis_i, rids_i, CD, Wl1, Wr1, att1, b1,
                                             2, nullptr, batch_i, w.pool_i, w, stream);
        run_group_thin<unsigned short, true>(srcA1_j, dstA1_j, eis_j, rids_j, CD, Wl1, Wr1, att1, b1,
                                             2, nullptr, batch_j, w.pool_j, w, stream);
    }

    head_kernel<<<BG, 128, 0, stream>>>(w.pool_i, w.pool_j, W_out, b_out,
                                        W_i, b_i, W_j, b_j, out);
}